// Round 17
// baseline (311.895 us; speedup 1.0000x reference)
//
#include <hip/hip_runtime.h>
#include <stdint.h>

#define NSEQ 512
#define DDIM 128
#define NROWS (NSEQ * NSEQ)   // 262144

typedef __bf16 bf16x8 __attribute__((ext_vector_type(8)));
typedef __bf16 bf16x2v __attribute__((ext_vector_type(2)));
typedef unsigned short u16;
typedef u16 ushort8 __attribute__((ext_vector_type(8)));
typedef float f32x4 __attribute__((ext_vector_type(4)));
typedef uint32_t u32x4 __attribute__((ext_vector_type(4)));
typedef uint32_t u32x2 __attribute__((ext_vector_type(2)));

__device__ __forceinline__ u16 cvt1(float f) {
  return __builtin_bit_cast(u16, (__bf16)f);
}
__device__ __forceinline__ uint32_t pk2(float a, float b) {
  bf16x2v v = {(__bf16)a, (__bf16)b};
  return __builtin_bit_cast(uint32_t, v);
}
__device__ __forceinline__ float bf2f(u16 u) {
  uint32_t x = ((uint32_t)u) << 16;
  return __builtin_bit_cast(float, x);
}
__device__ __forceinline__ f32x4 mfma_bf16(ushort8 a, ushort8 b, f32x4 c) {
  return __builtin_amdgcn_mfma_f32_16x16x32_bf16(
      __builtin_bit_cast(bf16x8, a), __builtin_bit_cast(bf16x8, b), c, 0, 0, 0);
}
__device__ __forceinline__ float sigmoidf_(float x) {
  return __builtin_amdgcn_rcpf(1.0f + __expf(-x));
}

// DPP ROW_ROR rotate (within 16-lane rows), pure-VALU cross-lane
#define ROR16(v, n)                                                            \
  __builtin_bit_cast(float, __builtin_amdgcn_update_dpp(                       \
      __builtin_bit_cast(int, (v)), __builtin_bit_cast(int, (v)),              \
      0x120 + (n), 0xF, 0xF, false))

#define GLOAD16(gp, lp)                                                        \
  __builtin_amdgcn_global_load_lds(                                            \
      (const __attribute__((address_space(1))) void*)(gp),                     \
      (__attribute__((address_space(3))) void*)(lp), 16, 0, 0)

// ---------------------------------------------------------------------------
// K0: weight prep, 128 blocks (r7/r10 verbatim).
// ---------------------------------------------------------------------------
__global__ __launch_bounds__(256) void k0_prep(
    const float* __restrict__ p_in_w, const float* __restrict__ g_in_w,
    const float* __restrict__ p_out_w, const float* __restrict__ g_out_w,
    const float* __restrict__ now, const float* __restrict__ nob,
    u16* __restrict__ Wb, u16* __restrict__ Pb, u16* __restrict__ Gb,
    float* __restrict__ S12) {
  const int b = blockIdx.x, t = threadIdx.x;
#pragma unroll
  for (int k = 0; k < 2; ++k) {
    const int idx = b * 512 + k * 256 + t;  // [0, 65536)
    const float v = (idx < 32768) ? p_in_w[idx] : g_in_w[idx - 32768];
    Wb[idx] = cvt1(v);
  }
  if (t < 128) {
    const int idx = b * 128 + t;  // [0, 16384)
    const int d = idx & 127;
    Pb[idx] = cvt1(p_out_w[idx] * now[d]);
    Gb[idx] = cvt1(g_out_w[idx]);
  }
  const int w = t >> 6, lane = t & 63;
  if (w >= 2) {
    const float* wv = (w == 2) ? now : nob;
    float p = p_out_w[b * 128 + lane] * wv[lane] +
              p_out_w[b * 128 + 64 + lane] * wv[64 + lane];
#pragma unroll
    for (int m = 1; m < 64; m <<= 1) p += __shfl_xor(p, m);
    if (lane == 0) S12[2 * b + (w - 2)] = p;
  }
}

// ---------------------------------------------------------------------------
// K1 (r16 verbatim, new best): 2-way cg split LN + dual projection.
// ---------------------------------------------------------------------------
__global__ __launch_bounds__(256, 4) void k1_ln_proj(
    const float* __restrict__ x, const float* __restrict__ mask,
    const float* __restrict__ niw, const float* __restrict__ nib,
    const u16* __restrict__ Wb, const u16* __restrict__ Gb,
    u16* __restrict__ AtB, u16* __restrict__ gArg) {
  __shared__ __align__(16) u16 xln[64 * 128];    // 16KB, 16B-granule XOR swizzle
  __shared__ __align__(16) u16 stage[128 * 64];  // 16KB [e_loc][k]; reused as stage2
  const int tid = threadIdx.x;
  const int lane = tid & 63;
  const int w = tid >> 6;
  const int bid = blockIdx.x;
  const int rb = (bid >> 4) * 8 + (bid & 7);  // [0,4096)
  const int cg = (bid >> 3) & 1;
  const int r0 = rb * 64;
  const int g = lane >> 4, c = lane & 15;

  // --- LN phase ---
  f32x4 v0[4], v1[4];
#pragma unroll
  for (int it = 0; it < 4; ++it) {
    const int rl = w * 16 + it * 4 + g;
    const float* xr = x + (size_t)(r0 + rl) * DDIM + c * 8;
    v0[it] = *(const f32x4*)xr;
    v1[it] = *(const f32x4*)(xr + 4);
  }
  const f32x4 w0 = *(const f32x4*)(niw + c * 8);
  const f32x4 w1 = *(const f32x4*)(niw + c * 8 + 4);
  const f32x4 b0 = *(const f32x4*)(nib + c * 8);
  const f32x4 b1 = *(const f32x4*)(nib + c * 8 + 4);
#pragma unroll
  for (int it = 0; it < 4; ++it) {
    const int rl = w * 16 + it * 4 + g;
    float s = v0[it][0] + v0[it][1] + v0[it][2] + v0[it][3] +
              v1[it][0] + v1[it][1] + v1[it][2] + v1[it][3];
    float ss = v0[it][0] * v0[it][0] + v0[it][1] * v0[it][1] +
               v0[it][2] * v0[it][2] + v0[it][3] * v0[it][3] +
               v1[it][0] * v1[it][0] + v1[it][1] * v1[it][1] +
               v1[it][2] * v1[it][2] + v1[it][3] * v1[it][3];
    { float t1 = ROR16(s, 1); s += t1; t1 = ROR16(ss, 1); ss += t1; }
    { float t1 = ROR16(s, 2); s += t1; t1 = ROR16(ss, 2); ss += t1; }
    { float t1 = ROR16(s, 4); s += t1; t1 = ROR16(ss, 4); ss += t1; }
    { float t1 = ROR16(s, 8); s += t1; t1 = ROR16(ss, 8); ss += t1; }
    const float mu = s * (1.0f / 128.0f);
    const float rs = rsqrtf(ss * (1.0f / 128.0f) - mu * mu + 1e-5f);
    float f0 = (v0[it][0] - mu) * rs * w0[0] + b0[0];
    float f1 = (v0[it][1] - mu) * rs * w0[1] + b0[1];
    float f2 = (v0[it][2] - mu) * rs * w0[2] + b0[2];
    float f3 = (v0[it][3] - mu) * rs * w0[3] + b0[3];
    float f4 = (v1[it][0] - mu) * rs * w1[0] + b1[0];
    float f5 = (v1[it][1] - mu) * rs * w1[1] + b1[1];
    float f6 = (v1[it][2] - mu) * rs * w1[2] + b1[2];
    float f7 = (v1[it][3] - mu) * rs * w1[3] + b1[3];
    u32x4 ov{pk2(f0, f1), pk2(f2, f3), pk2(f4, f5), pk2(f6, f7)};
    const int byteoff = rl * 256 + ((c ^ (rl & 7)) << 4);
    *(u32x4*)((char*)xln + byteoff) = ov;
  }
  __syncthreads();

  // --- MFMA pass 1: wave w -> P cols eP..eP+32, G +256 ---
  const int lr = lane & 15, lq = lane >> 4;
  const int eP = cg * 128 + w * 32;
  f32x4 accP[4][2], accG[4][2];
#pragma unroll
  for (int m = 0; m < 4; ++m)
#pragma unroll
    for (int n = 0; n < 2; ++n) {
      accP[m][n] = f32x4{0.f, 0.f, 0.f, 0.f};
      accG[m][n] = f32x4{0.f, 0.f, 0.f, 0.f};
    }
#pragma unroll
  for (int ks = 0; ks < 4; ++ks) {
    const int kblk = ks * 4 + lq;
    ushort8 af[4];
#pragma unroll
    for (int m = 0; m < 4; ++m) {
      const int row = m * 16 + lr;
      af[m] = *(const ushort8*)((const char*)xln + row * 256 +
                                ((kblk ^ (row & 7)) << 4));
    }
    ushort8 bP[2], bG[2];
#pragma unroll
    for (int n = 0; n < 2; ++n) {
      const int e = eP + n * 16 + lr;
      const int dd = ks * 32 + lq * 8;
      bP[n] = *(const ushort8*)(Wb + e * 128 + dd);
      bG[n] = *(const ushort8*)(Wb + (256 + e) * 128 + dd);
    }
#pragma unroll
    for (int m = 0; m < 4; ++m)
#pragma unroll
      for (int n = 0; n < 2; ++n) {
        accP[m][n] = mfma_bf16(af[m], bP[n], accP[m][n]);
        accG[m][n] = mfma_bf16(af[m], bG[n], accG[m][n]);
      }
  }

  // --- epilogue: gate + mask -> swizzled LDS stage [e_loc][k], 128 rows ---
#pragma unroll
  for (int m = 0; m < 4; ++m) {
    const int rloc = m * 16 + lq * 4;
    const f32x4 mv = *(const f32x4*)(mask + r0 + rloc);
#pragma unroll
    for (int n = 0; n < 2; ++n) {
      const int dloc = w * 32 + n * 16 + lr;  // e_loc in [0,128)
      const float o0 = accP[m][n][0] * sigmoidf_(accG[m][n][0]) * mv[0];
      const float o1 = accP[m][n][1] * sigmoidf_(accG[m][n][1]) * mv[1];
      const float o2 = accP[m][n][2] * sigmoidf_(accG[m][n][2]) * mv[2];
      const float o3 = accP[m][n][3] * sigmoidf_(accG[m][n][3]) * mv[3];
      u32x2 pk;
      pk[0] = pk2(o0, o1);
      pk[1] = pk2(o2, o3);
      const int gsw = (m * 4 + lq) ^ (dloc & 15);  // 8B granule XOR swizzle
      *(u32x2*)((char*)stage + dloc * 128 + (gsw << 3)) = pk;
    }
  }
  __syncthreads();

  // --- write: ONE contiguous 16KB run AtB[kt][i][cg*128 + e_loc][k_in] ---
  {
    const int i_ = rb >> 3, kt = rb & 7;
    u16* dst = AtB + (((size_t)kt * 512 + i_) * 256 + cg * 128) * 64;
#pragma unroll
    for (int q = 0; q < 4; ++q) {
      const int e = q * 32 + (tid >> 3);   // plane within 128
      const int g0 = (tid & 7) * 2;        // 8B granule pair
      const u32x2 lo =
          *(const u32x2*)((const char*)stage + e * 128 + ((g0 ^ (e & 15)) << 3));
      const u32x2 hi = *(const u32x2*)((const char*)stage + e * 128 +
                                       (((g0 + 1) ^ (e & 15)) << 3));
      u32x4 outv{lo[0], lo[1], hi[0], hi[1]};
      *(u32x4*)(dst + e * 64 + (tid & 7) * 8) = outv;
    }
  }

  // --- MFMA pass 2 (cg in {0,1}): gArg = xln @ g_out^T ---
  {
    f32x4 accO[4];
#pragma unroll
    for (int m = 0; m < 4; ++m) accO[m] = f32x4{0.f, 0.f, 0.f, 0.f};
    const int eg = cg * 64 + w * 16 + lr;
#pragma unroll
    for (int ks = 0; ks < 4; ++ks) {
      const int kblk = ks * 4 + lq;
      const ushort8 bO = *(const ushort8*)(Gb + eg * 128 + ks * 32 + lq * 8);
#pragma unroll
      for (int m = 0; m < 4; ++m) {
        const int row = m * 16 + lr;
        const ushort8 af2 = *(const ushort8*)((const char*)xln + row * 256 +
                                              ((kblk ^ (row & 7)) << 4));
        accO[m] = mfma_bf16(af2, bO, accO[m]);
      }
    }
    __syncthreads();  // all threads done reading `stage` -> safe to alias
    u16* stage2 = stage;
    const int e_loc = w * 16 + lr;        // [0,64)
    const int gsl = e_loc >> 2;           // logical 8B granule [0,16)
    const int esub = (e_loc & 3) * 2;     // byte within granule
#pragma unroll
    for (int m = 0; m < 4; ++m) {
#pragma unroll
      for (int reg = 0; reg < 4; ++reg) {
        const int rl2 = m * 16 + lq * 4 + reg;
        *(u16*)((char*)stage2 + rl2 * 128 + ((gsl ^ (rl2 & 7)) << 3) + esub) =
            cvt1(accO[m][reg]);
      }
    }
    __syncthreads();
#pragma unroll
    for (int p = 0; p < 2; ++p) {
      const int r = p * 32 + (tid >> 3);
      const int il8 = tid & 7;
      const char* base = (const char*)stage2 + r * 128;
      const u32x2 a = *(const u32x2*)(base + (((il8 * 2) ^ (r & 7)) << 3));
      const u32x2 b = *(const u32x2*)(base + (((il8 * 2 + 1) ^ (r & 7)) << 3));
      u32x4 ov{a[0], a[1], b[0], b[1]};
      *(u32x4*)(gArg + (size_t)(r0 + r) * DDIM + cg * 64 + il8 * 8) = ov;
    }
  }
}

// ---------------------------------------------------------------------------
// K2: per-d GEMM from blocked AtB (r13 main loop). NEW: C written to the
// k3-consumer-blocked layout Ct2[rband][d][r_in] (rband = r>>7 = i*4 + j0/128).
// ---------------------------------------------------------------------------
__global__ __launch_bounds__(256, 4) void k2_tri(const u16* __restrict__ AtB,
                                                 u16* __restrict__ Ct2) {
  __shared__ __align__(16) u16 lds[16384];  // [A:8192 | B:8192] elems = 32KB
  const int tid = threadIdx.x;
  const int bid = blockIdx.x;
  const int lb = (bid & 7) * 256 + (bid >> 3);
  const int d = lb >> 4;
  const int tile = lb & 15;
  const int i0 = (tile >> 2) * 128, j0 = (tile & 3) * 128;
  const int lane = tid & 63, wid = tid >> 6;
  const int wr = wid >> 1, wc = wid & 1;
  const int lr = lane & 15, lq = lane >> 4;

  f32x4 acc[4][4];
#pragma unroll
  for (int m = 0; m < 4; ++m)
#pragma unroll
    for (int n = 0; n < 4; ++n) acc[m][n] = f32x4{0.f, 0.f, 0.f, 0.f};

  for (int kt = 0; kt < 8; ++kt) {
    if (kt) __syncthreads();
#pragma unroll
    for (int q = 0; q < 4; ++q) {
      const int idx = q * 256 + tid;  // 0..1023
      const int r = idx >> 3, bk = idx & 7;
      const int sbk = bk ^ (r & 7);  // pre-swizzled global source
      GLOAD16(AtB + (((size_t)kt * 512 + i0 + r) * 256 + d) * 64 + sbk * 8,
              &lds[idx * 8]);
      GLOAD16(AtB + (((size_t)kt * 512 + j0 + r) * 256 + 128 + d) * 64 + sbk * 8,
              &lds[8192 + idx * 8]);
    }
    __syncthreads();

    const u16* A_l = lds;
    const u16* B_l = lds + 8192;
#pragma unroll
    for (int ks = 0; ks < 2; ++ks) {
      const int kblk = ks * 4 + lq;
      ushort8 af[4], bfr[4];
#pragma unroll
      for (int m = 0; m < 4; ++m) {
        const int row = wr * 64 + m * 16 + lr;
        af[m] = *(const ushort8*)((const char*)A_l + row * 128 +
                                  ((kblk ^ (row & 7)) << 4));
      }
#pragma unroll
      for (int n = 0; n < 4; ++n) {
        const int col = wc * 64 + n * 16 + lr;
        bfr[n] = *(const ushort8*)((const char*)B_l + col * 128 +
                                   ((kblk ^ (col & 7)) << 4));
      }
#pragma unroll
      for (int m = 0; m < 4; ++m)
#pragma unroll
        for (int n = 0; n < 4; ++n)
          acc[m][n] = mfma_bf16(af[m], bfr[n], acc[m][n]);
    }
  }

  // C-write into Ct2[rband][d][r_in]: rband = i*4 + j0/128, r_in = j - j0.
  const int jq = j0 >> 7;
#pragma unroll
  for (int m = 0; m < 4; ++m) {
    const int i = i0 + wr * 64 + m * 16 + lq * 4;
#pragma unroll
    for (int n = 0; n < 4; ++n) {
      const int jl = wc * 64 + n * 16 + lr;  // r_in in [0,128)
#pragma unroll
      for (int reg = 0; reg < 4; ++reg)
        Ct2[((size_t)((i + reg) * 4 + jq) * 128 + d) * 128 + jl] =
            cvt1(acc[m][n][reg]);
    }
  }
}

// ---------------------------------------------------------------------------
// K3 (rewritten phase A): block rband reads its contiguous 32KB Ct2 band
// (16B/lane streaming), transposes into ldsT[r][d ^ (c8<<3)], recomputes
// per-row stats from LDS, then MFMA/epilogue as before (new swizzle key).
// ---------------------------------------------------------------------------
__global__ __launch_bounds__(256, 4) void k3_out(
    const u16* __restrict__ Ct2, const u16* __restrict__ gArg,
    const u16* __restrict__ Pb, const float* __restrict__ S12,
    float* __restrict__ out) {
  __shared__ __align__(16) u16 ldsT[128 * 128];  // [r][dsw], dsw = d ^ (c8<<3)
  __shared__ float ps[256], pss[256];
  __shared__ float prm[128 * 2];
  __shared__ float s12l[128 * 2];
  const int tid = threadIdx.x, lane = tid & 63, w = tid >> 6;
  const int rband = blockIdx.x;
  const int c0 = rband * 128;

  // --- phase A: contiguous stream + LDS transpose ---
  {
    const u16* src = Ct2 + (size_t)rband * 16384;
    const int c8 = lane & 15;
    ushort8 ch[8];
#pragma unroll
    for (int q = 0; q < 8; ++q) {
      const int d = w * 32 + q * 4 + (lane >> 4);
      ch[q] = *(const ushort8*)(src + d * 128 + c8 * 8);
    }
#pragma unroll
    for (int q = 0; q < 8; ++q) {
      const int d = w * 32 + q * 4 + (lane >> 4);
      const int dsw = d ^ (c8 << 3);
#pragma unroll
      for (int j = 0; j < 8; ++j) {
        const int r = c8 * 8 + j;
        ldsT[r * 128 + dsw] = ch[q][j];
      }
    }
  }
  if (tid < 128) ((u32x2*)s12l)[tid] = ((const u32x2*)S12)[tid];
  __syncthreads();

  // --- stats: per-row sums over d, from LDS ---
  {
    const int row = tid & 127, half = tid >> 7;
    float s = 0.f, ss = 0.f;
#pragma unroll
    for (int k = 0; k < 8; ++k) {
      const int kblk = half * 8 + k;
      const ushort8 v = *(const ushort8*)((const char*)ldsT + row * 256 +
                                          ((kblk ^ ((row >> 3) & 15)) << 4));
#pragma unroll
      for (int j = 0; j < 8; ++j) {
        const float f = bf2f(v[j]);
        s += f;
        ss += f * f;
      }
    }
    ps[half * 128 + row] = s;
    pss[half * 128 + row] = ss;
  }
  __syncthreads();
  if (tid < 128) {
    const float s = ps[tid] + ps[128 + tid];
    const float ss = pss[tid] + pss[128 + tid];
    const float mu = s * (1.f / 128.f);
    const float rs = rsqrtf(ss * (1.f / 128.f) - mu * mu + 1e-5f);
    prm[2 * tid] = rs;
    prm[2 * tid + 1] = -rs * mu;
  }

  // --- MFMA: wave w owns rows [w*32, w*32+32), all 128 e cols ---
  const int lr = lane & 15, lq = lane >> 4;
  const int rowbase = w * 32;
  f32x4 aP[2][8];
#pragma unroll
  for (int m = 0; m < 2; ++m)
#pragma unroll
    for (int n = 0; n < 8; ++n) aP[m][n] = f32x4{0.f, 0.f, 0.f, 0.f};
#pragma unroll
  for (int ks = 0; ks < 4; ++ks) {
    const int kblk = ks * 4 + lq;
    ushort8 at2[2];
#pragma unroll
    for (int m = 0; m < 2; ++m) {
      const int row = rowbase + m * 16 + lr;
      at2[m] = *(const ushort8*)((const char*)ldsT + row * 256 +
                                 ((kblk ^ ((row >> 3) & 15)) << 4));
    }
    ushort8 bp[8];
#pragma unroll
    for (int n = 0; n < 8; ++n) {
      const int e = n * 16 + lr;
      bp[n] = *(const ushort8*)(Pb + e * 128 + ks * 32 + lq * 8);
    }
#pragma unroll
    for (int m = 0; m < 2; ++m)
#pragma unroll
      for (int n = 0; n < 8; ++n) aP[m][n] = mfma_bf16(at2[m], bp[n], aP[m][n]);
  }
  __syncthreads();  // prm/s12l ready for epilogue

  // --- epilogue ---
#pragma unroll
  for (int m = 0; m < 2; ++m) {
    const int crow = rowbase + m * 16 + lq * 4;
#pragma unroll
    for (int n = 0; n < 8; ++n) {
      const int e = n * 16 + lr;
      const float s1 = s12l[2 * e], s2v = s12l[2 * e + 1];
#pragma unroll
      for (int reg = 0; reg < 4; ++reg) {
        const float rs = prm[2 * (crow + reg)];
        const float t1 = prm[2 * (crow + reg) + 1];
        const float op = rs * aP[m][n][reg] + t1 * s1 + s2v;
        const size_t r = (size_t)(c0 + crow + reg);
        const float gt = sigmoidf_(bf2f(gArg[r * DDIM + e]));
        out[r * DDIM + e] = op * gt;
      }
    }
  }
}

// ---------------------------------------------------------------------------
extern "C" void kernel_launch(void* const* d_in, const int* in_sizes, int n_in,
                              void* d_out, int out_size, void* d_ws,
                              size_t ws_size, hipStream_t stream) {
  const float* x = (const float*)d_in[0];
  const float* mask = (const float*)d_in[1];
  const float* niw = (const float*)d_in[2];
  const float* nib = (const float*)d_in[3];
  const float* p_in_w = (const float*)d_in[4];
  const float* g_in_w = (const float*)d_in[5];
  const float* now = (const float*)d_in[6];
  const float* nob = (const float*)d_in[7];
  const float* p_out_w = (const float*)d_in[8];
  const float* g_out_w = (const float*)d_in[9];
  float* out = (float*)d_out;
  char* ws = (char*)d_ws;

  u16* AtB = (u16*)(ws);                  // 128 MiB (blocked a|b planes)
  u16* Ct2 = (u16*)(ws + 134217728);      // 64 MiB (k3-blocked layout)
  u16* gA = (u16*)(ws + 201326592);       // 64 MiB
  u16* Wb = (u16*)(ws + 268435456);       // 128 KiB
  u16* Pb = (u16*)(ws + 268566528);       // 32 KiB
  u16* Gb = (u16*)(ws + 268599296);       // 32 KiB
  float* S12 = (float*)(ws + 268632064);  // 1 KiB

  hipLaunchKernelGGL(k0_prep, dim3(128), dim3(256), 0, stream, p_in_w, g_in_w,
                     p_out_w, g_out_w, now, nob, Wb, Pb, Gb, S12);
  hipLaunchKernelGGL(k1_ln_proj, dim3(2 * NROWS / 64), dim3(256), 0, stream, x,
                     mask, niw, nib, Wb, Gb, AtB, gA);
  hipLaunchKernelGGL(k2_tri, dim3(128 * 16), dim3(256), 0, stream, AtB, Ct2);
  hipLaunchKernelGGL(k3_out, dim3(NROWS / 128), dim3(256), 0, stream, Ct2, gA,
                     Pb, S12, out);
}

// Round 18
// 306.971 us; speedup vs baseline: 1.0160x; 1.0160x over previous
//
#include <hip/hip_runtime.h>
#include <stdint.h>

#define NSEQ 512
#define DDIM 128
#define NROWS (NSEQ * NSEQ)   // 262144

typedef __bf16 bf16x8 __attribute__((ext_vector_type(8)));
typedef __bf16 bf16x2v __attribute__((ext_vector_type(2)));
typedef unsigned short u16;
typedef u16 ushort8 __attribute__((ext_vector_type(8)));
typedef float f32x4 __attribute__((ext_vector_type(4)));
typedef uint32_t u32x4 __attribute__((ext_vector_type(4)));
typedef uint32_t u32x2 __attribute__((ext_vector_type(2)));

__device__ __forceinline__ u16 cvt1(float f) {
  return __builtin_bit_cast(u16, (__bf16)f);
}
__device__ __forceinline__ uint32_t pk2(float a, float b) {
  bf16x2v v = {(__bf16)a, (__bf16)b};
  return __builtin_bit_cast(uint32_t, v);
}
__device__ __forceinline__ float bf2f(u16 u) {
  uint32_t x = ((uint32_t)u) << 16;
  return __builtin_bit_cast(float, x);
}
__device__ __forceinline__ f32x4 mfma_bf16(ushort8 a, ushort8 b, f32x4 c) {
  return __builtin_amdgcn_mfma_f32_16x16x32_bf16(
      __builtin_bit_cast(bf16x8, a), __builtin_bit_cast(bf16x8, b), c, 0, 0, 0);
}
__device__ __forceinline__ float sigmoidf_(float x) {
  return __builtin_amdgcn_rcpf(1.0f + __expf(-x));
}

// DPP ROW_ROR rotate (within 16-lane rows), pure-VALU cross-lane
#define ROR16(v, n)                                                            \
  __builtin_bit_cast(float, __builtin_amdgcn_update_dpp(                       \
      __builtin_bit_cast(int, (v)), __builtin_bit_cast(int, (v)),              \
      0x120 + (n), 0xF, 0xF, false))

#define GLOAD16(gp, lp)                                                        \
  __builtin_amdgcn_global_load_lds(                                            \
      (const __attribute__((address_space(1))) void*)(gp),                     \
      (__attribute__((address_space(3))) void*)(lp), 16, 0, 0)

// ---------------------------------------------------------------------------
// K0: weight prep, 128 blocks (r7/r10 verbatim).
// ---------------------------------------------------------------------------
__global__ __launch_bounds__(256) void k0_prep(
    const float* __restrict__ p_in_w, const float* __restrict__ g_in_w,
    const float* __restrict__ p_out_w, const float* __restrict__ g_out_w,
    const float* __restrict__ now, const float* __restrict__ nob,
    u16* __restrict__ Wb, u16* __restrict__ Pb, u16* __restrict__ Gb,
    float* __restrict__ S12) {
  const int b = blockIdx.x, t = threadIdx.x;
#pragma unroll
  for (int k = 0; k < 2; ++k) {
    const int idx = b * 512 + k * 256 + t;  // [0, 65536)
    const float v = (idx < 32768) ? p_in_w[idx] : g_in_w[idx - 32768];
    Wb[idx] = cvt1(v);
  }
  if (t < 128) {
    const int idx = b * 128 + t;  // [0, 16384)
    const int d = idx & 127;
    Pb[idx] = cvt1(p_out_w[idx] * now[d]);
    Gb[idx] = cvt1(g_out_w[idx]);
  }
  const int w = t >> 6, lane = t & 63;
  if (w >= 2) {
    const float* wv = (w == 2) ? now : nob;
    float p = p_out_w[b * 128 + lane] * wv[lane] +
              p_out_w[b * 128 + 64 + lane] * wv[64 + lane];
#pragma unroll
    for (int m = 1; m < 64; m <<= 1) p += __shfl_xor(p, m);
    if (lane == 0) S12[2 * b + (w - 2)] = p;
  }
}

// ---------------------------------------------------------------------------
// K1 (8-wave, x read ONCE): one 512-thread block per 64-row slab covers all
// 256 P + 256 G cols. Per-wave math identical to r16 (32P+32G cols, 64-f32
// acc); AtB write is one contiguous 32KB run; gArg written as full 256B rows.
// ---------------------------------------------------------------------------
__global__ __launch_bounds__(512, 4) void k1_ln_proj(
    const float* __restrict__ x, const float* __restrict__ mask,
    const float* __restrict__ niw, const float* __restrict__ nib,
    const u16* __restrict__ Wb, const u16* __restrict__ Gb,
    u16* __restrict__ AtB, u16* __restrict__ gArg) {
  __shared__ __align__(16) u16 xln[64 * 128];    // 16KB, 16B-granule XOR swizzle
  __shared__ __align__(16) u16 stage[256 * 64];  // 32KB [e_loc][k]; reused as stage2
  const int tid = threadIdx.x;
  const int lane = tid & 63;
  const int w = tid >> 6;  // [0,8)
  const int bid = blockIdx.x;
  const int rb = (bid >> 3) * 8 + (bid & 7);  // [0,4096), XCD-striped
  const int r0 = rb * 64;
  const int g = lane >> 4, c = lane & 15;

  // --- LN phase: wave w rows [w*8, w*8+8), 4 rows/iter, 2 iters ---
  f32x4 v0[2], v1[2];
#pragma unroll
  for (int it = 0; it < 2; ++it) {
    const int rl = w * 8 + it * 4 + g;
    const float* xr = x + (size_t)(r0 + rl) * DDIM + c * 8;
    v0[it] = *(const f32x4*)xr;
    v1[it] = *(const f32x4*)(xr + 4);
  }
  const f32x4 w0 = *(const f32x4*)(niw + c * 8);
  const f32x4 w1 = *(const f32x4*)(niw + c * 8 + 4);
  const f32x4 b0 = *(const f32x4*)(nib + c * 8);
  const f32x4 b1 = *(const f32x4*)(nib + c * 8 + 4);
#pragma unroll
  for (int it = 0; it < 2; ++it) {
    const int rl = w * 8 + it * 4 + g;
    float s = v0[it][0] + v0[it][1] + v0[it][2] + v0[it][3] +
              v1[it][0] + v1[it][1] + v1[it][2] + v1[it][3];
    float ss = v0[it][0] * v0[it][0] + v0[it][1] * v0[it][1] +
               v0[it][2] * v0[it][2] + v0[it][3] * v0[it][3] +
               v1[it][0] * v1[it][0] + v1[it][1] * v1[it][1] +
               v1[it][2] * v1[it][2] + v1[it][3] * v1[it][3];
    { float t1 = ROR16(s, 1); s += t1; t1 = ROR16(ss, 1); ss += t1; }
    { float t1 = ROR16(s, 2); s += t1; t1 = ROR16(ss, 2); ss += t1; }
    { float t1 = ROR16(s, 4); s += t1; t1 = ROR16(ss, 4); ss += t1; }
    { float t1 = ROR16(s, 8); s += t1; t1 = ROR16(ss, 8); ss += t1; }
    const float mu = s * (1.0f / 128.0f);
    const float rs = rsqrtf(ss * (1.0f / 128.0f) - mu * mu + 1e-5f);
    float f0 = (v0[it][0] - mu) * rs * w0[0] + b0[0];
    float f1 = (v0[it][1] - mu) * rs * w0[1] + b0[1];
    float f2 = (v0[it][2] - mu) * rs * w0[2] + b0[2];
    float f3 = (v0[it][3] - mu) * rs * w0[3] + b0[3];
    float f4 = (v1[it][0] - mu) * rs * w1[0] + b1[0];
    float f5 = (v1[it][1] - mu) * rs * w1[1] + b1[1];
    float f6 = (v1[it][2] - mu) * rs * w1[2] + b1[2];
    float f7 = (v1[it][3] - mu) * rs * w1[3] + b1[3];
    u32x4 ov{pk2(f0, f1), pk2(f2, f3), pk2(f4, f5), pk2(f6, f7)};
    const int byteoff = rl * 256 + ((c ^ (rl & 7)) << 4);
    *(u32x4*)((char*)xln + byteoff) = ov;
  }
  __syncthreads();

  // --- MFMA pass 1: wave w -> P cols [w*32, w*32+32), G cols +256 ---
  const int lr = lane & 15, lq = lane >> 4;
  const int eP = w * 32;
  f32x4 accP[4][2], accG[4][2];
#pragma unroll
  for (int m = 0; m < 4; ++m)
#pragma unroll
    for (int n = 0; n < 2; ++n) {
      accP[m][n] = f32x4{0.f, 0.f, 0.f, 0.f};
      accG[m][n] = f32x4{0.f, 0.f, 0.f, 0.f};
    }
#pragma unroll
  for (int ks = 0; ks < 4; ++ks) {
    const int kblk = ks * 4 + lq;
    ushort8 af[4];
#pragma unroll
    for (int m = 0; m < 4; ++m) {
      const int row = m * 16 + lr;
      af[m] = *(const ushort8*)((const char*)xln + row * 256 +
                                ((kblk ^ (row & 7)) << 4));
    }
    ushort8 bP[2], bG[2];
#pragma unroll
    for (int n = 0; n < 2; ++n) {
      const int e = eP + n * 16 + lr;
      const int dd = ks * 32 + lq * 8;
      bP[n] = *(const ushort8*)(Wb + e * 128 + dd);
      bG[n] = *(const ushort8*)(Wb + (256 + e) * 128 + dd);
    }
#pragma unroll
    for (int m = 0; m < 4; ++m)
#pragma unroll
      for (int n = 0; n < 2; ++n) {
        accP[m][n] = mfma_bf16(af[m], bP[n], accP[m][n]);
        accG[m][n] = mfma_bf16(af[m], bG[n], accG[m][n]);
      }
  }

  // --- epilogue: gate + mask -> swizzled LDS stage [e_loc][k], 256 rows ---
#pragma unroll
  for (int m = 0; m < 4; ++m) {
    const int rloc = m * 16 + lq * 4;
    const f32x4 mv = *(const f32x4*)(mask + r0 + rloc);
#pragma unroll
    for (int n = 0; n < 2; ++n) {
      const int dloc = w * 32 + n * 16 + lr;  // e_loc in [0,256)
      const float o0 = accP[m][n][0] * sigmoidf_(accG[m][n][0]) * mv[0];
      const float o1 = accP[m][n][1] * sigmoidf_(accG[m][n][1]) * mv[1];
      const float o2 = accP[m][n][2] * sigmoidf_(accG[m][n][2]) * mv[2];
      const float o3 = accP[m][n][3] * sigmoidf_(accG[m][n][3]) * mv[3];
      u32x2 pk;
      pk[0] = pk2(o0, o1);
      pk[1] = pk2(o2, o3);
      const int gsw = (m * 4 + lq) ^ (dloc & 15);  // 8B granule XOR swizzle
      *(u32x2*)((char*)stage + dloc * 128 + (gsw << 3)) = pk;
    }
  }
  __syncthreads();

  // --- write: ONE contiguous 32KB run AtB[kt][i][e 0..256)[k_in] ---
  {
    const int i_ = rb >> 3, kt = rb & 7;
    u16* dst = AtB + ((size_t)kt * 512 + i_) * 256 * 64;
#pragma unroll
    for (int q = 0; q < 4; ++q) {
      const int e = q * 64 + (tid >> 3);   // plane within 256
      const int g0 = (tid & 7) * 2;        // 8B granule pair
      const u32x2 lo =
          *(const u32x2*)((const char*)stage + e * 128 + ((g0 ^ (e & 15)) << 3));
      const u32x2 hi = *(const u32x2*)((const char*)stage + e * 128 +
                                       (((g0 + 1) ^ (e & 15)) << 3));
      u32x4 outv{lo[0], lo[1], hi[0], hi[1]};
      *(u32x4*)(dst + e * 64 + (tid & 7) * 8) = outv;
    }
  }

  // --- MFMA pass 2: gArg = xln @ g_out^T; wave w -> eg in [w*16, w*16+16) ---
  {
    f32x4 accO[4];
#pragma unroll
    for (int m = 0; m < 4; ++m) accO[m] = f32x4{0.f, 0.f, 0.f, 0.f};
    const int eg = w * 16 + lr;  // [0,128)
#pragma unroll
    for (int ks = 0; ks < 4; ++ks) {
      const int kblk = ks * 4 + lq;
      const ushort8 bO = *(const ushort8*)(Gb + eg * 128 + ks * 32 + lq * 8);
#pragma unroll
      for (int m = 0; m < 4; ++m) {
        const int row = m * 16 + lr;
        const ushort8 af2 = *(const ushort8*)((const char*)xln + row * 256 +
                                              ((kblk ^ (row & 7)) << 4));
        accO[m] = mfma_bf16(af2, bO, accO[m]);
      }
    }
    __syncthreads();  // all threads done reading `stage` -> safe to alias
    // stage2[r 0..64)[e 0..128): 256B rows, 32x 8B granules, XOR-swizzled
    u16* stage2 = stage;
    const int e_loc = eg;                 // [0,128)
    const int gsl = e_loc >> 2;           // granule [0,32)
    const int esub = (e_loc & 3) * 2;     // byte within granule
#pragma unroll
    for (int m = 0; m < 4; ++m) {
#pragma unroll
      for (int reg = 0; reg < 4; ++reg) {
        const int rl2 = m * 16 + lq * 4 + reg;  // row [0,64)
        *(u16*)((char*)stage2 + rl2 * 256 + ((gsl ^ (rl2 & 7)) << 3) + esub) =
            cvt1(accO[m][reg]);
      }
    }
    __syncthreads();
    // read-back: full 256B gArg rows, 16 threads per row
#pragma unroll
    for (int p = 0; p < 2; ++p) {
      const int r = p * 32 + (tid >> 4);   // [0,64)
      const int il16 = tid & 15;
      const char* base = (const char*)stage2 + r * 256;
      const u32x2 a = *(const u32x2*)(base + (((il16 * 2) ^ (r & 7)) << 3));
      const u32x2 b = *(const u32x2*)(base + (((il16 * 2 + 1) ^ (r & 7)) << 3));
      u32x4 ov{a[0], a[1], b[0], b[1]};
      *(u32x4*)(gArg + (size_t)(r0 + r) * DDIM + il16 * 8) = ov;
    }
  }
}

// ---------------------------------------------------------------------------
// K2: per-d GEMM from blocked AtB (r17 verbatim: single 32KB buffer, Ct2 out).
// ---------------------------------------------------------------------------
__global__ __launch_bounds__(256, 4) void k2_tri(const u16* __restrict__ AtB,
                                                 u16* __restrict__ Ct2) {
  __shared__ __align__(16) u16 lds[16384];  // [A:8192 | B:8192] elems = 32KB
  const int tid = threadIdx.x;
  const int bid = blockIdx.x;
  const int lb = (bid & 7) * 256 + (bid >> 3);
  const int d = lb >> 4;
  const int tile = lb & 15;
  const int i0 = (tile >> 2) * 128, j0 = (tile & 3) * 128;
  const int lane = tid & 63, wid = tid >> 6;
  const int wr = wid >> 1, wc = wid & 1;
  const int lr = lane & 15, lq = lane >> 4;

  f32x4 acc[4][4];
#pragma unroll
  for (int m = 0; m < 4; ++m)
#pragma unroll
    for (int n = 0; n < 4; ++n) acc[m][n] = f32x4{0.f, 0.f, 0.f, 0.f};

  for (int kt = 0; kt < 8; ++kt) {
    if (kt) __syncthreads();
#pragma unroll
    for (int q = 0; q < 4; ++q) {
      const int idx = q * 256 + tid;  // 0..1023
      const int r = idx >> 3, bk = idx & 7;
      const int sbk = bk ^ (r & 7);  // pre-swizzled global source
      GLOAD16(AtB + (((size_t)kt * 512 + i0 + r) * 256 + d) * 64 + sbk * 8,
              &lds[idx * 8]);
      GLOAD16(AtB + (((size_t)kt * 512 + j0 + r) * 256 + 128 + d) * 64 + sbk * 8,
              &lds[8192 + idx * 8]);
    }
    __syncthreads();

    const u16* A_l = lds;
    const u16* B_l = lds + 8192;
#pragma unroll
    for (int ks = 0; ks < 2; ++ks) {
      const int kblk = ks * 4 + lq;
      ushort8 af[4], bfr[4];
#pragma unroll
      for (int m = 0; m < 4; ++m) {
        const int row = wr * 64 + m * 16 + lr;
        af[m] = *(const ushort8*)((const char*)A_l + row * 128 +
                                  ((kblk ^ (row & 7)) << 4));
      }
#pragma unroll
      for (int n = 0; n < 4; ++n) {
        const int col = wc * 64 + n * 16 + lr;
        bfr[n] = *(const ushort8*)((const char*)B_l + col * 128 +
                                   ((kblk ^ (col & 7)) << 4));
      }
#pragma unroll
      for (int m = 0; m < 4; ++m)
#pragma unroll
        for (int n = 0; n < 4; ++n)
          acc[m][n] = mfma_bf16(af[m], bfr[n], acc[m][n]);
    }
  }

  // C-write into Ct2[rband][d][r_in]: rband = i*4 + j0/128, r_in = j - j0.
  const int jq = j0 >> 7;
#pragma unroll
  for (int m = 0; m < 4; ++m) {
    const int i = i0 + wr * 64 + m * 16 + lq * 4;
#pragma unroll
    for (int n = 0; n < 4; ++n) {
      const int jl = wc * 64 + n * 16 + lr;  // r_in in [0,128)
#pragma unroll
      for (int reg = 0; reg < 4; ++reg)
        Ct2[((size_t)((i + reg) * 4 + jq) * 128 + d) * 128 + jl] =
            cvt1(acc[m][n][reg]);
    }
  }
}

// ---------------------------------------------------------------------------
// K3 (r17 verbatim): contiguous Ct2 band stream + LDS transpose + MFMA.
// ---------------------------------------------------------------------------
__global__ __launch_bounds__(256, 4) void k3_out(
    const u16* __restrict__ Ct2, const u16* __restrict__ gArg,
    const u16* __restrict__ Pb, const float* __restrict__ S12,
    float* __restrict__ out) {
  __shared__ __align__(16) u16 ldsT[128 * 128];  // [r][dsw], dsw = d ^ (c8<<3)
  __shared__ float ps[256], pss[256];
  __shared__ float prm[128 * 2];
  __shared__ float s12l[128 * 2];
  const int tid = threadIdx.x, lane = tid & 63, w = tid >> 6;
  const int rband = blockIdx.x;
  const int c0 = rband * 128;

  // --- phase A: contiguous stream + LDS transpose ---
  {
    const u16* src = Ct2 + (size_t)rband * 16384;
    const int c8 = lane & 15;
    ushort8 ch[8];
#pragma unroll
    for (int q = 0; q < 8; ++q) {
      const int d = w * 32 + q * 4 + (lane >> 4);
      ch[q] = *(const ushort8*)(src + d * 128 + c8 * 8);
    }
#pragma unroll
    for (int q = 0; q < 8; ++q) {
      const int d = w * 32 + q * 4 + (lane >> 4);
      const int dsw = d ^ (c8 << 3);
#pragma unroll
      for (int j = 0; j < 8; ++j) {
        const int r = c8 * 8 + j;
        ldsT[r * 128 + dsw] = ch[q][j];
      }
    }
  }
  if (tid < 128) ((u32x2*)s12l)[tid] = ((const u32x2*)S12)[tid];
  __syncthreads();

  // --- stats: per-row sums over d, from LDS ---
  {
    const int row = tid & 127, half = tid >> 7;
    float s = 0.f, ss = 0.f;
#pragma unroll
    for (int k = 0; k < 8; ++k) {
      const int kblk = half * 8 + k;
      const ushort8 v = *(const ushort8*)((const char*)ldsT + row * 256 +
                                          ((kblk ^ ((row >> 3) & 15)) << 4));
#pragma unroll
      for (int j = 0; j < 8; ++j) {
        const float f = bf2f(v[j]);
        s += f;
        ss += f * f;
      }
    }
    ps[half * 128 + row] = s;
    pss[half * 128 + row] = ss;
  }
  __syncthreads();
  if (tid < 128) {
    const float s = ps[tid] + ps[128 + tid];
    const float ss = pss[tid] + pss[128 + tid];
    const float mu = s * (1.f / 128.f);
    const float rs = rsqrtf(ss * (1.f / 128.f) - mu * mu + 1e-5f);
    prm[2 * tid] = rs;
    prm[2 * tid + 1] = -rs * mu;
  }

  // --- MFMA: wave w owns rows [w*32, w*32+32), all 128 e cols ---
  const int lr = lane & 15, lq = lane >> 4;
  const int rowbase = w * 32;
  f32x4 aP[2][8];
#pragma unroll
  for (int m = 0; m < 2; ++m)
#pragma unroll
    for (int n = 0; n < 8; ++n) aP[m][n] = f32x4{0.f, 0.f, 0.f, 0.f};
#pragma unroll
  for (int ks = 0; ks < 4; ++ks) {
    const int kblk = ks * 4 + lq;
    ushort8 at2[2];
#pragma unroll
    for (int m = 0; m < 2; ++m) {
      const int row = rowbase + m * 16 + lr;
      at2[m] = *(const ushort8*)((const char*)ldsT + row * 256 +
                                 ((kblk ^ ((row >> 3) & 15)) << 4));
    }
    ushort8 bp[8];
#pragma unroll
    for (int n = 0; n < 8; ++n) {
      const int e = n * 16 + lr;
      bp[n] = *(const ushort8*)(Pb + e * 128 + ks * 32 + lq * 8);
    }
#pragma unroll
    for (int m = 0; m < 2; ++m)
#pragma unroll
      for (int n = 0; n < 8; ++n) aP[m][n] = mfma_bf16(at2[m], bp[n], aP[m][n]);
  }
  __syncthreads();  // prm/s12l ready for epilogue

  // --- epilogue ---
#pragma unroll
  for (int m = 0; m < 2; ++m) {
    const int crow = rowbase + m * 16 + lq * 4;
#pragma unroll
    for (int n = 0; n < 8; ++n) {
      const int e = n * 16 + lr;
      const float s1 = s12l[2 * e], s2v = s12l[2 * e + 1];
#pragma unroll
      for (int reg = 0; reg < 4; ++reg) {
        const float rs = prm[2 * (crow + reg)];
        const float t1 = prm[2 * (crow + reg) + 1];
        const float op = rs * aP[m][n][reg] + t1 * s1 + s2v;
        const size_t r = (size_t)(c0 + crow + reg);
        const float gt = sigmoidf_(bf2f(gArg[r * DDIM + e]));
        out[r * DDIM + e] = op * gt;
      }
    }
  }
}

// ---------------------------------------------------------------------------
extern "C" void kernel_launch(void* const* d_in, const int* in_sizes, int n_in,
                              void* d_out, int out_size, void* d_ws,
                              size_t ws_size, hipStream_t stream) {
  const float* x = (const float*)d_in[0];
  const float* mask = (const float*)d_in[1];
  const float* niw = (const float*)d_in[2];
  const float* nib = (const float*)d_in[3];
  const float* p_in_w = (const float*)d_in[4];
  const float* g_in_w = (const float*)d_in[5];
  const float* now = (const float*)d_in[6];
  const float* nob = (const float*)d_in[7];
  const float* p_out_w = (const float*)d_in[8];
  const float* g_out_w = (const float*)d_in[9];
  float* out = (float*)d_out;
  char* ws = (char*)d_ws;

  u16* AtB = (u16*)(ws);                  // 128 MiB (blocked a|b planes)
  u16* Ct2 = (u16*)(ws + 134217728);      // 64 MiB (k3-blocked layout)
  u16* gA = (u16*)(ws + 201326592);       // 64 MiB
  u16* Wb = (u16*)(ws + 268435456);       // 128 KiB
  u16* Pb = (u16*)(ws + 268566528);       // 32 KiB
  u16* Gb = (u16*)(ws + 268599296);       // 32 KiB
  float* S12 = (float*)(ws + 268632064);  // 1 KiB

  hipLaunchKernelGGL(k0_prep, dim3(128), dim3(256), 0, stream, p_in_w, g_in_w,
                     p_out_w, g_out_w, now, nob, Wb, Pb, Gb, S12);
  hipLaunchKernelGGL(k1_ln_proj, dim3(NROWS / 64), dim3(512), 0, stream, x,
                     mask, niw, nib, Wb, Gb, AtB, gA);
  hipLaunchKernelGGL(k2_tri, dim3(128 * 16), dim3(256), 0, stream, AtB, Ct2);
  hipLaunchKernelGGL(k3_out, dim3(NROWS / 128), dim3(256), 0, stream, Ct2, gA,
                     Pb, S12, out);
}